// Round 6
// baseline (77473.456 us; speedup 1.0000x reference)
//
#include <hip/hip_runtime.h>
#include <hip/hip_bf16.h>

// SLAHead decode: B=64, T=784, C=H=512, 501 steps.
// Persistent kernel, 256 blocks x 1024 thr (1 block/CU co-resident).
// Relaxed agent-scope atomics only (no fences / no L2 wb-inv scans).
// R6: feat quantized to fp8-e4m3 (stream 51->25.7 MB/step, 3.2 MB/XCD fits
// L2); attention re-fused by prefetching ALL feat rows into registers before
// the LDS score pass (full latency overlap); phases B/C hoist coherent loads.

#define NB 64
#define TT 784
#define CC 512
#define HH 512
#define NCLS 30
#define LREG 8
#define STEPS 501
#define GRID_MAIN 256
#define THR_MAIN 1024

typedef float floatx2 __attribute__((ext_vector_type(2)));

struct SlaP {
  unsigned char* feat8;     // [B][T][C] fp8 e4m3
  unsigned char* scr8;      // [B][T][H] fp8 e4m3 (feat_proj)
  float* hid2;              // [2][H/2][B][2] ping-pong, pair-interleaved
  float* hproj;             // [B][H]
  float* h1sg;              // [B][H]
  float* h1lg;              // [B][H]
  float* ctx2;              // [C/2][B][2] combined raw context (atomicAdd)
  float* wsum;              // [B]
  int*   chars;             // [B]
  unsigned* bar;            // [0]=master cnt, [64]=gen, [8+32x]=per-XCD cnt
  const float *score_w, *w_ih, *w_hh, *b_ih, *b_hh;
  const float *h2h_w, *h2h_b, *sg1_w, *sg1_b, *sg2_w, *sg2_b;
  const float *lg1_w, *lg1_b, *lg2_w, *lg2_b;
  float *out_probs, *out_loc;
};

__device__ __forceinline__ float cld(const float* p){
  return __hip_atomic_load(p, __ATOMIC_RELAXED, __HIP_MEMORY_SCOPE_AGENT);
}
__device__ __forceinline__ void cst(float* p, float v){
  __hip_atomic_store(p, v, __ATOMIC_RELAXED, __HIP_MEMORY_SCOPE_AGENT);
}
__device__ __forceinline__ int cldi(const int* p){
  return __hip_atomic_load(p, __ATOMIC_RELAXED, __HIP_MEMORY_SCOPE_AGENT);
}
__device__ __forceinline__ void csti(int* p, int v){
  __hip_atomic_store(p, v, __ATOMIC_RELAXED, __HIP_MEMORY_SCOPE_AGENT);
}
__device__ __forceinline__ float2 cld2(const float* p){
  unsigned long long v = __hip_atomic_load((const unsigned long long*)p,
                          __ATOMIC_RELAXED, __HIP_MEMORY_SCOPE_AGENT);
  union { unsigned long long u; float2 f; } c; c.u = v; return c.f;
}
__device__ __forceinline__ void cst2(float* p, float a, float b){
  union { unsigned long long u; float2 f; } c; c.f = make_float2(a, b);
  __hip_atomic_store((unsigned long long*)p, c.u,
                     __ATOMIC_RELAXED, __HIP_MEMORY_SCOPE_AGENT);
}

__device__ __forceinline__ float tanh_fast(float x){
  float ex = __expf(2.f * x);
  return 1.f - 2.f * __builtin_amdgcn_rcpf(ex + 1.f);
}
__device__ __forceinline__ float sigmoid_fast(float x){
  return __builtin_amdgcn_rcpf(1.f + __expf(-x));
}
__device__ __forceinline__ float warp_sum(float v){
  #pragma unroll
  for (int m = 32; m > 0; m >>= 1) v += __shfl_xor(v, m, 64);
  return v;
}
__device__ __forceinline__ float warp_max(float v){
  #pragma unroll
  for (int m = 32; m > 0; m >>= 1) v = fmaxf(v, __shfl_xor(v, m, 64));
  return v;
}
__device__ __forceinline__ int warp_min_i(int v){
  #pragma unroll
  for (int m = 32; m > 0; m >>= 1) v = min(v, __shfl_xor(v, m, 64));
  return v;
}

// Monotone fence-free grid barrier (relaxed agent atomics only).
__device__ __forceinline__ void gbar(unsigned* bar, unsigned target){
  __syncthreads();
  if (threadIdx.x == 0){
    unsigned* c8 = bar + 8 + (blockIdx.x & 7) * 32;
    unsigned p = __hip_atomic_fetch_add(c8, 1u, __ATOMIC_RELAXED, __HIP_MEMORY_SCOPE_AGENT);
    if (p == 32u * target - 1u){
      unsigned pm = __hip_atomic_fetch_add(bar, 1u, __ATOMIC_RELAXED, __HIP_MEMORY_SCOPE_AGENT);
      if (pm == 8u * target - 1u)
        __hip_atomic_store(bar + 64, target, __ATOMIC_RELAXED, __HIP_MEMORY_SCOPE_AGENT);
    }
    while (__hip_atomic_load(bar + 64, __ATOMIC_RELAXED, __HIP_MEMORY_SCOPE_AGENT) < target)
      __builtin_amdgcn_s_sleep(1);
  }
  __syncthreads();
}

// ---------------- setup kernels ----------------

__global__ void k_init(SlaP p){
  int idx = blockIdx.x * blockDim.x + threadIdx.x;  // 32768 threads
  if (idx < 32768){ p.hid2[idx] = 0.f; p.ctx2[idx] = 0.f; }
  if (idx < 64*512) p.hproj[idx] = p.h2h_b[idx & 511];
  if (idx < 64){ p.wsum[idx] = 0.f; p.chars[idx] = 0; }
  if (idx < 512) p.bar[idx] = 0u;
}

// feat8[b][t][c] = fp8_e4m3(fea[b][c][t]) via LDS-tiled transpose
__global__ void k_feat8(const float* __restrict__ fea, unsigned char* __restrict__ feat8){
  __shared__ float tile[64][65];
  const int b = blockIdx.z, t0 = blockIdx.x * 64, c0 = blockIdx.y * 64;
  #pragma unroll
  for (int r = 0; r < 16; ++r){
    int idx = threadIdx.x + 256*r;
    int ci = idx >> 6, tj = idx & 63;
    float v = 0.f;
    if (t0 + tj < TT) v = fea[((size_t)b*CC + (c0+ci))*TT + t0 + tj];
    tile[ci][tj] = v;
  }
  __syncthreads();
  #pragma unroll
  for (int r = 0; r < 4; ++r){
    int idx = threadIdx.x + 256*r;      // 1024 items: t(64) x cgroup(16)
    int t = idx >> 4, cg = idx & 15;
    if (t0 + t < TT){
      float a = tile[cg*4+0][t], b2 = tile[cg*4+1][t];
      float c = tile[cg*4+2][t], d = tile[cg*4+3][t];
      int pk = __builtin_amdgcn_cvt_pk_fp8_f32(a, b2, 0, false);
      pk = __builtin_amdgcn_cvt_pk_fp8_f32(c, d, pk, true);
      *(int*)&feat8[((size_t)b*TT + t0 + t)*512 + c0 + cg*4] = pk;
    }
  }
}

// scr8[b][t][h] = fp8_e4m3( sum_c fea[b][c][t] * i2h[h][c] )
__global__ void k_fpgemm(const float* __restrict__ fea, const float* __restrict__ i2h,
                         unsigned char* __restrict__ scr8){
  const int b = blockIdx.z, t0 = blockIdx.x * 64, h0 = blockIdx.y * 64;
  const int tx = threadIdx.x & 15, ty = threadIdx.x >> 4;
  const int tb = t0 + tx*4, hb = h0 + ty*4;
  const int ts = (tb < TT) ? tb : 0;
  const float* A = fea + (size_t)b*CC*TT;
  float acc[4][4];
  #pragma unroll
  for (int j = 0; j < 4; ++j)
    #pragma unroll
    for (int i2 = 0; i2 < 4; ++i2) acc[j][i2] = 0.f;
  for (int k = 0; k < CC; ++k){
    const float4 a4 = *(const float4*)&A[(size_t)k*TT + ts];
    float bv0 = i2h[(size_t)(hb+0)*CC + k];
    float bv1 = i2h[(size_t)(hb+1)*CC + k];
    float bv2 = i2h[(size_t)(hb+2)*CC + k];
    float bv3 = i2h[(size_t)(hb+3)*CC + k];
    acc[0][0] += bv0*a4.x; acc[0][1] += bv0*a4.y; acc[0][2] += bv0*a4.z; acc[0][3] += bv0*a4.w;
    acc[1][0] += bv1*a4.x; acc[1][1] += bv1*a4.y; acc[1][2] += bv1*a4.z; acc[1][3] += bv1*a4.w;
    acc[2][0] += bv2*a4.x; acc[2][1] += bv2*a4.y; acc[2][2] += bv2*a4.z; acc[2][3] += bv2*a4.w;
    acc[3][0] += bv3*a4.x; acc[3][1] += bv3*a4.y; acc[3][2] += bv3*a4.z; acc[3][3] += bv3*a4.w;
  }
  if (tb < TT){
    #pragma unroll
    for (int i2 = 0; i2 < 4; ++i2){
      int pk = __builtin_amdgcn_cvt_pk_fp8_f32(acc[0][i2], acc[1][i2], 0, false);
      pk = __builtin_amdgcn_cvt_pk_fp8_f32(acc[2][i2], acc[3][i2], pk, true);
      *(int*)&scr8[((size_t)b*TT + tb + i2)*512 + hb] = pk;
    }
  }
}

// ---------------- persistent decode kernel ----------------

__global__ void __launch_bounds__(THR_MAIN, 4) sla_main(SlaP p){
  const int tid  = threadIdx.x;
  const int lane = tid & 63;
  const int wv   = tid >> 6;       // 16 waves
  const int blk  = blockIdx.x;     // 256 blocks
  __shared__ float sm[12352];      // 49.4 KB phase scratch
  __shared__ uint4 lsc4[6272];     // 100.4 KB: this block's 196 fp8 score rows
  unsigned char* lsc = (unsigned char*)lsc4;
  float* smF = sm + 12288;

  const int ab = blk >> 2;         // attention batch
  const int aslice = blk & 3;      // attention t-slice (4 x 196)
  float svr[8];
  #pragma unroll
  for (int k = 0; k < 8; ++k) svr[k] = p.score_w[lane*8 + k];

  // attention rows per wave: wv<4 -> 13 rows, else 12 (196 total)
  const int cnt = (wv < 4) ? 13 : 12;
  const int r0r = wv*12 + ((wv < 4) ? wv : 4);

  unsigned bid = 0;

  for (int i = 0; i <= STEPS; ++i){
    //================ Phase A: finals(i-1) + attention(i) ================
    if (i > 0 && blk < NB){
      const int fb = blk;
      for (int task = wv; task < 38; task += 16){
        const float* wrow; const float* src; float bias;
        if (task < 30){ wrow = p.sg2_w + task*512; bias = p.sg2_b[task]; src = p.h1sg + fb*512; }
        else          { wrow = p.lg2_w + (task-30)*512; bias = p.lg2_b[task-30]; src = p.h1lg + fb*512; }
        float s = 0.f;
        #pragma unroll
        for (int kq = 0; kq < 4; ++kq){
          const float2 wv2 = *(const float2*)&wrow[lane*2 + 128*kq];
          const float2 sv2 = cld2(&src[lane*2 + 128*kq]);
          s += wv2.x*sv2.x + wv2.y*sv2.y;
        }
        s = warp_sum(s);
        if (task < 30){ if (lane == 0) smF[task] = s + bias; }
        else if (lane == 0)
          p.out_loc[(size_t)fb*(STEPS*LREG) + (size_t)(i-1)*LREG + (task-30)] = sigmoid_fast(s + bias);
      }
    }
    __syncthreads();
    if (i > 0 && blk < NB && wv == 0){
      float sv_ = (lane < 30) ? smF[lane] : -3.4e38f;
      float m = warp_max(sv_);
      float e = (lane < 30) ? __expf(sv_ - m) : 0.f;
      float ssum = warp_sum(e);
      if (lane < 30)
        p.out_probs[(size_t)blk*(STEPS*NCLS) + (size_t)(i-1)*NCLS + lane] = e / ssum;
      int cand = (lane < 30 && sv_ == m) ? lane : 1000;
      cand = warp_min_i(cand);
      if (lane == 0) csti(&p.chars[blk], cand);
    }
    if (i == STEPS) break;
    if (i == 0){
      // one-time fill of LDS-resident fp8 score rows (this block's slice)
      const uint4* g = (const uint4*)(p.scr8 + ((size_t)ab*TT + aslice*196)*512);
      for (int idx = tid; idx < 6272; idx += THR_MAIN) lsc4[idx] = g[idx];
      __syncthreads();
    }
    {
      // ---- prefetch ALL feat fp8 rows into registers (overlaps pass 1) ----
      const unsigned char* ftB = p.feat8 + ((size_t)ab*TT + aslice*196)*512 + lane*8;
      uint2 fv[13];
      #pragma unroll
      for (int r = 0; r < 13; ++r)
        if (r < cnt) fv[r] = *(const uint2*)(ftB + (size_t)(r0r + r)*512);

      float hpr[8];
      #pragma unroll
      for (int k = 0; k < 4; ++k){
        float2 h2 = cld2(&p.hproj[ab*512 + lane*8 + 2*k]);
        hpr[2*k] = h2.x; hpr[2*k+1] = h2.y;
      }
      // ---- pass 1: scores from LDS (fp8 -> f32), batched reduction ----
      float e[13];
      #pragma unroll
      for (int r = 0; r < 13; ++r){
        if (r < cnt){
          const uint2 rd = *(const uint2*)&lsc[(r0r + r)*512 + lane*8];
          const floatx2 p01 = __builtin_amdgcn_cvt_pk_f32_fp8(rd.x, false);
          const floatx2 p23 = __builtin_amdgcn_cvt_pk_f32_fp8(rd.x, true);
          const floatx2 p45 = __builtin_amdgcn_cvt_pk_f32_fp8(rd.y, false);
          const floatx2 p67 = __builtin_amdgcn_cvt_pk_f32_fp8(rd.y, true);
          float s = 0.f;
          s += tanh_fast(p01.x + hpr[0]) * svr[0];
          s += tanh_fast(p01.y + hpr[1]) * svr[1];
          s += tanh_fast(p23.x + hpr[2]) * svr[2];
          s += tanh_fast(p23.y + hpr[3]) * svr[3];
          s += tanh_fast(p45.x + hpr[4]) * svr[4];
          s += tanh_fast(p45.y + hpr[5]) * svr[5];
          s += tanh_fast(p67.x + hpr[6]) * svr[6];
          s += tanh_fast(p67.y + hpr[7]) * svr[7];
          e[r] = s;
        } else e[r] = 0.f;
      }
      #pragma unroll
      for (int m = 32; m > 0; m >>= 1){
        #pragma unroll
        for (int r = 0; r < 13; ++r) e[r] += __shfl_xor(e[r], m, 64);
      }
      float w[13];
      float wsr = 0.f;
      #pragma unroll
      for (int r = 0; r < 13; ++r){
        if (r < cnt){ w[r] = __expf(e[r]); wsr += w[r]; }
        else w[r] = 0.f;
      }
      // ---- pass 2: consume prefetched feat registers ----
      float acc[8] = {0,0,0,0,0,0,0,0};
      #pragma unroll
      for (int r = 0; r < 13; ++r){
        if (r < cnt){
          const floatx2 f01 = __builtin_amdgcn_cvt_pk_f32_fp8(fv[r].x, false);
          const floatx2 f23 = __builtin_amdgcn_cvt_pk_f32_fp8(fv[r].x, true);
          const floatx2 f45 = __builtin_amdgcn_cvt_pk_f32_fp8(fv[r].y, false);
          const floatx2 f67 = __builtin_amdgcn_cvt_pk_f32_fp8(fv[r].y, true);
          const float wg = w[r];
          acc[0] += wg*f01.x; acc[1] += wg*f01.y;
          acc[2] += wg*f23.x; acc[3] += wg*f23.y;
          acc[4] += wg*f45.x; acc[5] += wg*f45.y;
          acc[6] += wg*f67.x; acc[7] += wg*f67.y;
        }
      }
      // two-round LDS reduction over 16 waves into sm[8][512]
      if (wv < 8){
        #pragma unroll
        for (int k = 0; k < 8; ++k) sm[wv*512 + lane*8 + k] = acc[k];
      }
      if (lane == 0) smF[32 + wv] = wsr;
      __syncthreads();
      if (wv >= 8){
        #pragma unroll
        for (int k = 0; k < 8; ++k) sm[(wv-8)*512 + lane*8 + k] += acc[k];
      }
      __syncthreads();
      if (tid < 512){
        float s = 0.f;
        #pragma unroll
        for (int r = 0; r < 8; ++r) s += sm[r*512 + tid];
        unsafeAtomicAdd(&p.ctx2[(tid >> 1)*128 + ab*2 + (tid & 1)], s);
      } else if (tid == 512){
        float s = 0.f;
        #pragma unroll
        for (int r = 0; r < 16; ++r) s += smF[32 + r];
        unsafeAtomicAdd(&p.wsum[ab], s);
      }
    }
    gbar(p.bar, ++bid);
    //================ Phase B: GRU, 128 blocks x 4 hidden rows ================
    if (blk < 128){
      const int j0 = blk * 4;
      const float* hidC = p.hid2 + (i & 1)*(512*64);
      const int kp0 = wv * 16;           // pair base for this wave's k range
      float accI[4][3], accH[4][3];
      #pragma unroll
      for (int jj = 0; jj < 4; ++jj)
        #pragma unroll
        for (int g = 0; g < 3; ++g){ accI[jj][g] = 0.f; accH[jj][g] = 0.f; }
      #pragma unroll
      for (int h = 0; h < 2; ++h){
        float2 xv[8], hv[8];
        #pragma unroll
        for (int t = 0; t < 8; ++t){
          xv[t] = cld2(&p.ctx2[(kp0 + h*8 + t)*128 + lane*2]);
          hv[t] = cld2(&hidC[(kp0 + h*8 + t)*128 + lane*2]);
        }
        #pragma unroll
        for (int q = 0; q < 4; ++q){
          const int k = wv*32 + h*16 + q*4;
          #pragma unroll
          for (int jj = 0; jj < 4; ++jj)
            #pragma unroll
            for (int g = 0; g < 3; ++g){
              const int row = g*512 + j0 + jj;
              const float4 wi = *(const float4*)&p.w_ih[(size_t)row*542 + k];
              const float4 wh = *(const float4*)&p.w_hh[(size_t)row*512 + k];
              accI[jj][g] += wi.x*xv[2*q].x + wi.y*xv[2*q].y + wi.z*xv[2*q+1].x + wi.w*xv[2*q+1].y;
              accH[jj][g] += wh.x*hv[2*q].x + wh.y*hv[2*q].y + wh.z*hv[2*q+1].x + wh.w*hv[2*q+1].y;
            }
        }
      }
      const int slot = wv & 7;
      if (wv < 8){
        #pragma unroll
        for (int jj = 0; jj < 4; ++jj)
          #pragma unroll
          for (int g = 0; g < 3; ++g){
            sm[((slot*24) + jj*6 + g    )*64 + lane] = accI[jj][g];
            sm[((slot*24) + jj*6 + 3 + g)*64 + lane] = accH[jj][g];
          }
      }
      __syncthreads();
      if (wv >= 8){
        #pragma unroll
        for (int jj = 0; jj < 4; ++jj)
          #pragma unroll
          for (int g = 0; g < 3; ++g){
            sm[((slot*24) + jj*6 + g    )*64 + lane] += accI[jj][g];
            sm[((slot*24) + jj*6 + 3 + g)*64 + lane] += accH[jj][g];
          }
      }
      __syncthreads();
      if (tid < 128){
        const int pp = tid >> 6;            // j-pair 0..1
        const int b = tid & 63;
        const float inv = 1.f / cld(&p.wsum[b]);
        const int ch = cldi(&p.chars[b]);
        const float2 ho = cld2(&hidC[((j0 >> 1) + pp)*128 + b*2]);
        float nh[2];
        #pragma unroll
        for (int q = 0; q < 2; ++q){
          const int jj = pp*2 + q;
          float gi[3], gh[3];
          #pragma unroll
          for (int g = 0; g < 3; ++g){
            float giS = 0.f, ghS = 0.f;
            #pragma unroll
            for (int sl = 0; sl < 8; ++sl){
              giS += sm[((sl*24) + jj*6 + g    )*64 + b];
              ghS += sm[((sl*24) + jj*6 + 3 + g)*64 + b];
            }
            const int row = g*512 + j0 + jj;
            gi[g] = giS*inv + p.w_ih[(size_t)row*542 + 512 + ch] + p.b_ih[row];
            gh[g] = ghS + p.b_hh[row];
          }
          float r_ = sigmoid_fast(gi[0] + gh[0]);
          float z_ = sigmoid_fast(gi[1] + gh[1]);
          float n_ = tanh_fast(gi[2] + r_*gh[2]);
          float hold = (q == 0) ? ho.x : ho.y;
          nh[q] = (1.f - z_)*n_ + z_*hold;
        }
        cst2(&p.hid2[((i+1) & 1)*(512*64) + ((j0 >> 1) + pp)*128 + b*2], nh[0], nh[1]);
      }
    } else {
      __syncthreads(); __syncthreads();
    }
    gbar(p.bar, ++bid);
    //================ Phase C: heads, 128 blocks x 12 rows; idle blocks zero ctx ================
    if (blk < 128){
      const int r0 = blk * 12;
      const float* hidN = p.hid2 + ((i+1) & 1)*(512*64);
      const float* rowp[12];
      #pragma unroll
      for (int r = 0; r < 12; ++r){
        const int rg = r0 + r, head = rg >> 9, j = rg & 511;
        const float* base = (head == 0) ? p.h2h_w : (head == 1) ? p.sg1_w : p.lg1_w;
        rowp[r] = base + (size_t)j*512;
      }
      float2 hv[16];
      #pragma unroll
      for (int t = 0; t < 16; ++t)
        hv[t] = cld2(&hidN[(wv*16 + t)*128 + lane*2]);
      float acc[12];
      #pragma unroll
      for (int r = 0; r < 12; ++r) acc[r] = 0.f;
      #pragma unroll
      for (int q = 0; q < 8; ++q){
        const int k = wv*32 + q*4;
        #pragma unroll
        for (int r = 0; r < 12; ++r){
          const float4 w4 = *(const float4*)&rowp[r][k];
          acc[r] += w4.x*hv[2*q].x + w4.y*hv[2*q].y + w4.z*hv[2*q+1].x + w4.w*hv[2*q+1].y;
        }
      }
      const int slot = wv & 7;
      if (wv < 8){
        #pragma unroll
        for (int r = 0; r < 12; ++r) sm[((slot*12) + r)*64 + lane] = acc[r];
      }
      __syncthreads();
      if (wv >= 8){
        #pragma unroll
        for (int r = 0; r < 12; ++r) sm[((slot*12) + r)*64 + lane] += acc[r];
      }
      __syncthreads();
      if (tid < 384){
        const int q = tid >> 6, b = tid & 63;   // row pair (2q, 2q+1)
        float s0 = 0.f, s1 = 0.f;
        #pragma unroll
        for (int sl = 0; sl < 8; ++sl){
          s0 += sm[((sl*12) + 2*q    )*64 + b];
          s1 += sm[((sl*12) + 2*q + 1)*64 + b];
        }
        const int rg = r0 + 2*q, head = rg >> 9, j = rg & 511;
        const float* bb = (head == 0) ? p.h2h_b : (head == 1) ? p.sg1_b : p.lg1_b;
        float* dst = (head == 0) ? p.hproj : (head == 1) ? p.h1sg : p.h1lg;
        cst2(&dst[b*512 + j], s0 + bb[j], s1 + bb[j+1]);
      }
    } else {
      const int bz = blk - 128;
      if (tid < 256) cst(&p.ctx2[bz*256 + tid], 0.f);
      if (bz == 127 && tid < 64) cst(&p.wsum[tid], 0.f);
      __syncthreads(); __syncthreads();
    }
    gbar(p.bar, ++bid);
  }
}

extern "C" void kernel_launch(void* const* d_in, const int* in_sizes, int n_in,
                              void* d_out, int out_size, void* d_ws, size_t ws_size,
                              hipStream_t stream){
  (void)in_sizes; (void)n_in; (void)out_size; (void)ws_size;
  char* w = (char*)d_ws;
  size_t off = 0;
  auto carve = [&](size_t bytes) -> char* {
    char* r = w + off; off += (bytes + 255) & ~(size_t)255; return r;
  };
  SlaP p;
  p.feat8  = (unsigned char*)carve((size_t)NB*TT*CC);
  p.scr8   = (unsigned char*)carve((size_t)NB*TT*HH);
  p.hid2   = (float*)carve((size_t)2*512*64*4);
  p.hproj  = (float*)carve((size_t)64*512*4);
  p.h1sg   = (float*)carve((size_t)64*512*4);
  p.h1lg   = (float*)carve((size_t)64*512*4);
  p.ctx2   = (float*)carve((size_t)512*64*4);
  p.wsum   = (float*)carve(64*4);
  p.chars  = (int*)carve(64*4);
  p.bar    = (unsigned*)carve(2048);

  p.score_w = (const float*)d_in[4];
  p.w_ih  = (const float*)d_in[5];  p.w_hh  = (const float*)d_in[6];
  p.b_ih  = (const float*)d_in[7];  p.b_hh  = (const float*)d_in[8];
  p.h2h_w = (const float*)d_in[2];  p.h2h_b = (const float*)d_in[3];
  p.sg1_w = (const float*)d_in[9];  p.sg1_b = (const float*)d_in[10];
  p.sg2_w = (const float*)d_in[11]; p.sg2_b = (const float*)d_in[12];
  p.lg1_w = (const float*)d_in[13]; p.lg1_b = (const float*)d_in[14];
  p.lg2_w = (const float*)d_in[15]; p.lg2_b = (const float*)d_in[16];
  p.out_probs = (float*)d_out;
  p.out_loc   = p.out_probs + (size_t)NB*STEPS*NCLS;

  const float* fea = (const float*)d_in[0];
  const float* i2h = (const float*)d_in[1];

  k_init<<<128, 256, 0, stream>>>(p);
  k_feat8<<<dim3(13, 8, 64), 256, 0, stream>>>(fea, p.feat8);
  k_fpgemm<<<dim3(13, 8, 64), 256, 0, stream>>>(fea, i2h, p.scr8);
  sla_main<<<GRID_MAIN, THR_MAIN, 0, stream>>>(p);
}

// Round 7
// 38288.837 us; speedup vs baseline: 2.0234x; 2.0234x over previous
//
#include <hip/hip_runtime.h>
#include <hip/hip_bf16.h>

// SLAHead decode: B=64, T=784, C=H=512, 501 steps.
// Persistent kernel, 256 blocks x 1024 thr (1 block/CU co-resident).
// Relaxed agent-scope atomics only (no fences / no L2 wb-inv scans).
// R7: fp8 feat stream + LDS-parked fp8 scores (R6 memory plan) with a
// low-register quad pipeline (4 rows at a time, depth-1 quad prefetch)
// -- R6's fv[13]/hv[16] register arrays spilled to scratch (32.7 GB of
// WRITE_SIZE); keep live arrays <= 8 elements. Phases B/C = R5 bodies.

#define NB 64
#define TT 784
#define CC 512
#define HH 512
#define NCLS 30
#define LREG 8
#define STEPS 501
#define GRID_MAIN 256
#define THR_MAIN 1024

typedef float floatx2 __attribute__((ext_vector_type(2)));

struct SlaP {
  unsigned char* feat8;     // [B][T][C] fp8 e4m3
  unsigned char* scr8;      // [B][T][H] fp8 e4m3 (feat_proj)
  float* hid2;              // [2][H/2][B][2] ping-pong, pair-interleaved
  float* hproj;             // [B][H]
  float* h1sg;              // [B][H]
  float* h1lg;              // [B][H]
  float* ctx2;              // [C/2][B][2] combined raw context (atomicAdd)
  float* wsum;              // [B]
  int*   chars;             // [B]
  unsigned* bar;            // [0]=master cnt, [64]=gen, [8+32x]=per-XCD cnt
  const float *score_w, *w_ih, *w_hh, *b_ih, *b_hh;
  const float *h2h_w, *h2h_b, *sg1_w, *sg1_b, *sg2_w, *sg2_b;
  const float *lg1_w, *lg1_b, *lg2_w, *lg2_b;
  float *out_probs, *out_loc;
};

__device__ __forceinline__ float cld(const float* p){
  return __hip_atomic_load(p, __ATOMIC_RELAXED, __HIP_MEMORY_SCOPE_AGENT);
}
__device__ __forceinline__ void cst(float* p, float v){
  __hip_atomic_store(p, v, __ATOMIC_RELAXED, __HIP_MEMORY_SCOPE_AGENT);
}
__device__ __forceinline__ int cldi(const int* p){
  return __hip_atomic_load(p, __ATOMIC_RELAXED, __HIP_MEMORY_SCOPE_AGENT);
}
__device__ __forceinline__ void csti(int* p, int v){
  __hip_atomic_store(p, v, __ATOMIC_RELAXED, __HIP_MEMORY_SCOPE_AGENT);
}
__device__ __forceinline__ float2 cld2(const float* p){
  unsigned long long v = __hip_atomic_load((const unsigned long long*)p,
                          __ATOMIC_RELAXED, __HIP_MEMORY_SCOPE_AGENT);
  union { unsigned long long u; float2 f; } c; c.u = v; return c.f;
}
__device__ __forceinline__ void cst2(float* p, float a, float b){
  union { unsigned long long u; float2 f; } c; c.f = make_float2(a, b);
  __hip_atomic_store((unsigned long long*)p, c.u,
                     __ATOMIC_RELAXED, __HIP_MEMORY_SCOPE_AGENT);
}

__device__ __forceinline__ float tanh_fast(float x){
  float ex = __expf(2.f * x);
  return 1.f - 2.f * __builtin_amdgcn_rcpf(ex + 1.f);
}
__device__ __forceinline__ float sigmoid_fast(float x){
  return __builtin_amdgcn_rcpf(1.f + __expf(-x));
}
__device__ __forceinline__ float warp_sum(float v){
  #pragma unroll
  for (int m = 32; m > 0; m >>= 1) v += __shfl_xor(v, m, 64);
  return v;
}
__device__ __forceinline__ float warp_max(float v){
  #pragma unroll
  for (int m = 32; m > 0; m >>= 1) v = fmaxf(v, __shfl_xor(v, m, 64));
  return v;
}
__device__ __forceinline__ int warp_min_i(int v){
  #pragma unroll
  for (int m = 32; m > 0; m >>= 1) v = min(v, __shfl_xor(v, m, 64));
  return v;
}

// per-lane score partial for one row held in LDS (fp8 x8)
__device__ __forceinline__ float score8(const unsigned char* lscrow,
                                        const float* hpr, const float* svr){
  const uint2 rd = *(const uint2*)lscrow;
  const floatx2 p01 = __builtin_amdgcn_cvt_pk_f32_fp8(rd.x, false);
  const floatx2 p23 = __builtin_amdgcn_cvt_pk_f32_fp8(rd.x, true);
  const floatx2 p45 = __builtin_amdgcn_cvt_pk_f32_fp8(rd.y, false);
  const floatx2 p67 = __builtin_amdgcn_cvt_pk_f32_fp8(rd.y, true);
  float s = 0.f;
  s += tanh_fast(p01.x + hpr[0]) * svr[0];
  s += tanh_fast(p01.y + hpr[1]) * svr[1];
  s += tanh_fast(p23.x + hpr[2]) * svr[2];
  s += tanh_fast(p23.y + hpr[3]) * svr[3];
  s += tanh_fast(p45.x + hpr[4]) * svr[4];
  s += tanh_fast(p45.y + hpr[5]) * svr[5];
  s += tanh_fast(p67.x + hpr[6]) * svr[6];
  s += tanh_fast(p67.y + hpr[7]) * svr[7];
  return s;
}

__device__ __forceinline__ void acc8(float* acc, uint2 fv, float wg){
  const floatx2 f01 = __builtin_amdgcn_cvt_pk_f32_fp8(fv.x, false);
  const floatx2 f23 = __builtin_amdgcn_cvt_pk_f32_fp8(fv.x, true);
  const floatx2 f45 = __builtin_amdgcn_cvt_pk_f32_fp8(fv.y, false);
  const floatx2 f67 = __builtin_amdgcn_cvt_pk_f32_fp8(fv.y, true);
  acc[0] += wg*f01.x; acc[1] += wg*f01.y;
  acc[2] += wg*f23.x; acc[3] += wg*f23.y;
  acc[4] += wg*f45.x; acc[5] += wg*f45.y;
  acc[6] += wg*f67.x; acc[7] += wg*f67.y;
}

// Monotone fence-free grid barrier (relaxed agent atomics only).
__device__ __forceinline__ void gbar(unsigned* bar, unsigned target){
  __syncthreads();
  if (threadIdx.x == 0){
    unsigned* c8 = bar + 8 + (blockIdx.x & 7) * 32;
    unsigned p = __hip_atomic_fetch_add(c8, 1u, __ATOMIC_RELAXED, __HIP_MEMORY_SCOPE_AGENT);
    if (p == 32u * target - 1u){
      unsigned pm = __hip_atomic_fetch_add(bar, 1u, __ATOMIC_RELAXED, __HIP_MEMORY_SCOPE_AGENT);
      if (pm == 8u * target - 1u)
        __hip_atomic_store(bar + 64, target, __ATOMIC_RELAXED, __HIP_MEMORY_SCOPE_AGENT);
    }
    while (__hip_atomic_load(bar + 64, __ATOMIC_RELAXED, __HIP_MEMORY_SCOPE_AGENT) < target)
      __builtin_amdgcn_s_sleep(1);
  }
  __syncthreads();
}

// ---------------- setup kernels ----------------

__global__ void k_init(SlaP p){
  int idx = blockIdx.x * blockDim.x + threadIdx.x;  // 32768 threads
  if (idx < 32768){ p.hid2[idx] = 0.f; p.ctx2[idx] = 0.f; }
  if (idx < 64*512) p.hproj[idx] = p.h2h_b[idx & 511];
  if (idx < 64){ p.wsum[idx] = 0.f; p.chars[idx] = 0; }
  if (idx < 512) p.bar[idx] = 0u;
}

// feat8[b][t][c] = fp8_e4m3(fea[b][c][t]) via LDS-tiled transpose
__global__ void k_feat8(const float* __restrict__ fea, unsigned char* __restrict__ feat8){
  __shared__ float tile[64][65];
  const int b = blockIdx.z, t0 = blockIdx.x * 64, c0 = blockIdx.y * 64;
  #pragma unroll
  for (int r = 0; r < 16; ++r){
    int idx = threadIdx.x + 256*r;
    int ci = idx >> 6, tj = idx & 63;
    float v = 0.f;
    if (t0 + tj < TT) v = fea[((size_t)b*CC + (c0+ci))*TT + t0 + tj];
    tile[ci][tj] = v;
  }
  __syncthreads();
  #pragma unroll
  for (int r = 0; r < 4; ++r){
    int idx = threadIdx.x + 256*r;      // 1024 items: t(64) x cgroup(16)
    int t = idx >> 4, cg = idx & 15;
    if (t0 + t < TT){
      float a = tile[cg*4+0][t], b2 = tile[cg*4+1][t];
      float c = tile[cg*4+2][t], d = tile[cg*4+3][t];
      int pk = __builtin_amdgcn_cvt_pk_fp8_f32(a, b2, 0, false);
      pk = __builtin_amdgcn_cvt_pk_fp8_f32(c, d, pk, true);
      *(int*)&feat8[((size_t)b*TT + t0 + t)*512 + c0 + cg*4] = pk;
    }
  }
}

// scr8[b][t][h] = fp8_e4m3( sum_c fea[b][c][t] * i2h[h][c] )
__global__ void k_fpgemm(const float* __restrict__ fea, const float* __restrict__ i2h,
                         unsigned char* __restrict__ scr8){
  const int b = blockIdx.z, t0 = blockIdx.x * 64, h0 = blockIdx.y * 64;
  const int tx = threadIdx.x & 15, ty = threadIdx.x >> 4;
  const int tb = t0 + tx*4, hb = h0 + ty*4;
  const int ts = (tb < TT) ? tb : 0;
  const float* A = fea + (size_t)b*CC*TT;
  float acc[4][4];
  #pragma unroll
  for (int j = 0; j < 4; ++j)
    #pragma unroll
    for (int i2 = 0; i2 < 4; ++i2) acc[j][i2] = 0.f;
  for (int k = 0; k < CC; ++k){
    const float4 a4 = *(const float4*)&A[(size_t)k*TT + ts];
    float bv0 = i2h[(size_t)(hb+0)*CC + k];
    float bv1 = i2h[(size_t)(hb+1)*CC + k];
    float bv2 = i2h[(size_t)(hb+2)*CC + k];
    float bv3 = i2h[(size_t)(hb+3)*CC + k];
    acc[0][0] += bv0*a4.x; acc[0][1] += bv0*a4.y; acc[0][2] += bv0*a4.z; acc[0][3] += bv0*a4.w;
    acc[1][0] += bv1*a4.x; acc[1][1] += bv1*a4.y; acc[1][2] += bv1*a4.z; acc[1][3] += bv1*a4.w;
    acc[2][0] += bv2*a4.x; acc[2][1] += bv2*a4.y; acc[2][2] += bv2*a4.z; acc[2][3] += bv2*a4.w;
    acc[3][0] += bv3*a4.x; acc[3][1] += bv3*a4.y; acc[3][2] += bv3*a4.z; acc[3][3] += bv3*a4.w;
  }
  if (tb < TT){
    #pragma unroll
    for (int i2 = 0; i2 < 4; ++i2){
      int pk = __builtin_amdgcn_cvt_pk_fp8_f32(acc[0][i2], acc[1][i2], 0, false);
      pk = __builtin_amdgcn_cvt_pk_fp8_f32(acc[2][i2], acc[3][i2], pk, true);
      *(int*)&scr8[((size_t)b*TT + tb + i2)*512 + hb] = pk;
    }
  }
}

// ---------------- persistent decode kernel ----------------

__global__ void __launch_bounds__(THR_MAIN, 4) sla_main(SlaP p){
  const int tid  = threadIdx.x;
  const int lane = tid & 63;
  const int wv   = tid >> 6;       // 16 waves
  const int blk  = blockIdx.x;     // 256 blocks
  __shared__ float sm[12352];      // 49.4 KB phase scratch
  __shared__ uint4 lsc4[6272];     // 100.4 KB: this block's 196 fp8 score rows
  unsigned char* lsc = (unsigned char*)lsc4;
  float* smF = sm + 12288;

  const int ab = blk >> 2;         // attention batch
  const int aslice = blk & 3;      // attention t-slice (4 x 196)
  float svr[8];
  #pragma unroll
  for (int k = 0; k < 8; ++k) svr[k] = p.score_w[lane*8 + k];

  // attention rows per wave: wv<4 -> 13 rows, else 12 (196 total)
  const int cnt = (wv < 4) ? 13 : 12;
  const int r0r = wv*12 + ((wv < 4) ? wv : 4);
  const int tcnt = cnt - 12;       // tail row count: 1 or 0

  unsigned bid = 0;

  for (int i = 0; i <= STEPS; ++i){
    //================ Phase A: finals(i-1) + attention(i) ================
    if (i > 0 && blk < NB){
      const int fb = blk;
      for (int task = wv; task < 38; task += 16){
        const float* wrow; const float* src; float bias;
        if (task < 30){ wrow = p.sg2_w + task*512; bias = p.sg2_b[task]; src = p.h1sg + fb*512; }
        else          { wrow = p.lg2_w + (task-30)*512; bias = p.lg2_b[task-30]; src = p.h1lg + fb*512; }
        float s = 0.f;
        #pragma unroll
        for (int kq = 0; kq < 4; ++kq){
          const float2 wv2 = *(const float2*)&wrow[lane*2 + 128*kq];
          const float2 sv2 = cld2(&src[lane*2 + 128*kq]);
          s += wv2.x*sv2.x + wv2.y*sv2.y;
        }
        s = warp_sum(s);
        if (task < 30){ if (lane == 0) smF[task] = s + bias; }
        else if (lane == 0)
          p.out_loc[(size_t)fb*(STEPS*LREG) + (size_t)(i-1)*LREG + (task-30)] = sigmoid_fast(s + bias);
      }
    }
    __syncthreads();
    if (i > 0 && blk < NB && wv == 0){
      float sv_ = (lane < 30) ? smF[lane] : -3.4e38f;
      float m = warp_max(sv_);
      float e = (lane < 30) ? __expf(sv_ - m) : 0.f;
      float ssum = warp_sum(e);
      if (lane < 30)
        p.out_probs[(size_t)blk*(STEPS*NCLS) + (size_t)(i-1)*NCLS + lane] = e / ssum;
      int cand = (lane < 30 && sv_ == m) ? lane : 1000;
      cand = warp_min_i(cand);
      if (lane == 0) csti(&p.chars[blk], cand);
    }
    if (i == STEPS) break;
    if (i == 0){
      // one-time fill of LDS-resident fp8 score rows (this block's slice)
      const uint4* g = (const uint4*)(p.scr8 + ((size_t)ab*TT + aslice*196)*512);
      for (int idx = tid; idx < 6272; idx += THR_MAIN) lsc4[idx] = g[idx];
      __syncthreads();
    }
    {
      float hpr[8];
      #pragma unroll
      for (int k = 0; k < 4; ++k){
        float2 h2 = cld2(&p.hproj[ab*512 + lane*8 + 2*k]);
        hpr[2*k] = h2.x; hpr[2*k+1] = h2.y;
      }
      const unsigned char* ftB = p.feat8 + ((size_t)ab*TT + aslice*196)*512 + lane*8;
      float acc[8] = {0,0,0,0,0,0,0,0};
      float wsr = 0.f;
      // quad pipeline: prefetch next 4 feat rows while scoring current 4 from LDS
      uint2 cur[4], nxt[4];
      #pragma unroll
      for (int j = 0; j < 4; ++j)
        cur[j] = *(const uint2*)(ftB + (size_t)(r0r + j)*512);
      #pragma unroll
      for (int q = 0; q < 3; ++q){
        if (q < 2){
          #pragma unroll
          for (int j = 0; j < 4; ++j)
            nxt[j] = *(const uint2*)(ftB + (size_t)(r0r + 4*(q+1) + j)*512);
        } else if (tcnt > 0){
          nxt[0] = *(const uint2*)(ftB + (size_t)(r0r + 12)*512);
        }
        float e[4];
        #pragma unroll
        for (int j = 0; j < 4; ++j)
          e[j] = score8(&lsc[(r0r + 4*q + j)*512 + lane*8], hpr, svr);
        #pragma unroll
        for (int m = 32; m > 0; m >>= 1){
          e[0] += __shfl_xor(e[0], m, 64);
          e[1] += __shfl_xor(e[1], m, 64);
          e[2] += __shfl_xor(e[2], m, 64);
          e[3] += __shfl_xor(e[3], m, 64);
        }
        #pragma unroll
        for (int j = 0; j < 4; ++j){
          const float wg = __expf(e[j]);
          wsr += wg;
          acc8(acc, cur[j], wg);
        }
        #pragma unroll
        for (int j = 0; j < 4; ++j) cur[j] = nxt[j];
      }
      if (tcnt > 0){
        float e0 = score8(&lsc[(r0r + 12)*512 + lane*8], hpr, svr);
        e0 = warp_sum(e0);
        const float wg = __expf(e0);
        wsr += wg;
        acc8(acc, cur[0], wg);
      }
      // two-round LDS reduction over 16 waves into sm[8][512]
      if (wv < 8){
        #pragma unroll
        for (int k = 0; k < 8; ++k) sm[wv*512 + lane*8 + k] = acc[k];
      }
      if (lane == 0) smF[32 + wv] = wsr;
      __syncthreads();
      if (wv >= 8){
        #pragma unroll
        for (int k = 0; k < 8; ++k) sm[(wv-8)*512 + lane*8 + k] += acc[k];
      }
      __syncthreads();
      if (tid < 512){
        float s = 0.f;
        #pragma unroll
        for (int r = 0; r < 8; ++r) s += sm[r*512 + tid];
        unsafeAtomicAdd(&p.ctx2[(tid >> 1)*128 + ab*2 + (tid & 1)], s);
      } else if (tid == 512){
        float s = 0.f;
        #pragma unroll
        for (int r = 0; r < 16; ++r) s += smF[32 + r];
        unsafeAtomicAdd(&p.wsum[ab], s);
      }
    }
    gbar(p.bar, ++bid);
    //================ Phase B: GRU, 128 blocks x 4 hidden rows ================
    if (blk < 128){
      const int j0 = blk * 4;
      const float* hidC = p.hid2 + (i & 1)*(512*64);
      float accI[4][3], accH[4][3];
      #pragma unroll
      for (int jj = 0; jj < 4; ++jj)
        #pragma unroll
        for (int g = 0; g < 3; ++g){ accI[jj][g] = 0.f; accH[jj][g] = 0.f; }
      const int kb = wv * 32;
      for (int kk = 0; kk < 32; kk += 4){
        const int k = kb + kk;
        const float2 x01 = cld2(&p.ctx2[(k >> 1)*128 + lane*2]);
        const float2 x23 = cld2(&p.ctx2[(k >> 1)*128 + 128 + lane*2]);
        const float2 h01 = cld2(&hidC[(k >> 1)*128 + lane*2]);
        const float2 h23 = cld2(&hidC[(k >> 1)*128 + 128 + lane*2]);
        #pragma unroll
        for (int jj = 0; jj < 4; ++jj)
          #pragma unroll
          for (int g = 0; g < 3; ++g){
            const int row = g*512 + j0 + jj;
            const float4 wi = *(const float4*)&p.w_ih[(size_t)row*542 + k];
            const float4 wh = *(const float4*)&p.w_hh[(size_t)row*512 + k];
            accI[jj][g] += wi.x*x01.x + wi.y*x01.y + wi.z*x23.x + wi.w*x23.y;
            accH[jj][g] += wh.x*h01.x + wh.y*h01.y + wh.z*h23.x + wh.w*h23.y;
          }
      }
      const int slot = wv & 7;
      if (wv < 8){
        #pragma unroll
        for (int jj = 0; jj < 4; ++jj)
          #pragma unroll
          for (int g = 0; g < 3; ++g){
            sm[((slot*24) + jj*6 + g    )*64 + lane] = accI[jj][g];
            sm[((slot*24) + jj*6 + 3 + g)*64 + lane] = accH[jj][g];
          }
      }
      __syncthreads();
      if (wv >= 8){
        #pragma unroll
        for (int jj = 0; jj < 4; ++jj)
          #pragma unroll
          for (int g = 0; g < 3; ++g){
            sm[((slot*24) + jj*6 + g    )*64 + lane] += accI[jj][g];
            sm[((slot*24) + jj*6 + 3 + g)*64 + lane] += accH[jj][g];
          }
      }
      __syncthreads();
      if (tid < 128){
        const int pp = tid >> 6;            // j-pair 0..1
        const int b = tid & 63;
        const float inv = 1.f / cld(&p.wsum[b]);
        const int ch = cldi(&p.chars[b]);
        const float2 ho = cld2(&hidC[((j0 >> 1) + pp)*128 + b*2]);
        float nh[2];
        #pragma unroll
        for (int q = 0; q < 2; ++q){
          const int jj = pp*2 + q;
          float gi[3], gh[3];
          #pragma unroll
          for (int g = 0; g < 3; ++g){
            float giS = 0.f, ghS = 0.f;
            #pragma unroll
            for (int sl = 0; sl < 8; ++sl){
              giS += sm[((sl*24) + jj*6 + g    )*64 + b];
              ghS += sm[((sl*24) + jj*6 + 3 + g)*64 + b];
            }
            const int row = g*512 + j0 + jj;
            gi[g] = giS*inv + p.w_ih[(size_t)row*542 + 512 + ch] + p.b_ih[row];
            gh[g] = ghS + p.b_hh[row];
          }
          float r_ = sigmoid_fast(gi[0] + gh[0]);
          float z_ = sigmoid_fast(gi[1] + gh[1]);
          float n_ = tanh_fast(gi[2] + r_*gh[2]);
          float hold = (q == 0) ? ho.x : ho.y;
          nh[q] = (1.f - z_)*n_ + z_*hold;
        }
        cst2(&p.hid2[((i+1) & 1)*(512*64) + ((j0 >> 1) + pp)*128 + b*2], nh[0], nh[1]);
      }
    } else {
      __syncthreads(); __syncthreads();
    }
    gbar(p.bar, ++bid);
    //================ Phase C: heads, 128 blocks x 12 rows; idle blocks zero ctx ================
    if (blk < 128){
      const int r0 = blk * 12;
      const float* hidN = p.hid2 + ((i+1) & 1)*(512*64);
      const float* rowp[12];
      #pragma unroll
      for (int r = 0; r < 12; ++r){
        const int rg = r0 + r, head = rg >> 9, j = rg & 511;
        const float* base = (head == 0) ? p.h2h_w : (head == 1) ? p.sg1_w : p.lg1_w;
        rowp[r] = base + (size_t)j*512;
      }
      float acc[12];
      #pragma unroll
      for (int r = 0; r < 12; ++r) acc[r] = 0.f;
      const int kb = wv * 32;
      for (int kk = 0; kk < 32; kk += 4){
        const int k = kb + kk;
        const float2 h01 = cld2(&hidN[(k >> 1)*128 + lane*2]);
        const float2 h23 = cld2(&hidN[(k >> 1)*128 + 128 + lane*2]);
        #pragma unroll
        for (int r = 0; r < 12; ++r){
          const float4 w4 = *(const float4*)&rowp[r][k];
          acc[r] += w4.x*h01.x + w4.y*h01.y + w4.z*h23.x + w4.w*h23.y;
        }
      }
      const int slot = wv & 7;
      if (wv < 8){
        #pragma unroll
        for (int r = 0; r < 12; ++r) sm[((slot*12) + r)*64 + lane] = acc[r];
      }
      __syncthreads();
      if (wv >= 8){
        #pragma unroll
        for (int r = 0; r < 12; ++r) sm[((slot*12) + r)*64 + lane] += acc[r];
      }
      __syncthreads();
      if (tid < 384){
        const int q = tid >> 6, b = tid & 63;   // row pair (2q, 2q+1)
        float s0 = 0.f, s1 = 0.f;
        #pragma unroll
        for (int sl = 0; sl < 8; ++sl){
          s0 += sm[((sl*12) + 2*q    )*64 + b];
          s1 += sm[((sl*12) + 2*q + 1)*64 + b];
        }
        const int rg = r0 + 2*q, head = rg >> 9, j = rg & 511;
        const float* bb = (head == 0) ? p.h2h_b : (head == 1) ? p.sg1_b : p.lg1_b;
        float* dst = (head == 0) ? p.hproj : (head == 1) ? p.h1sg : p.h1lg;
        cst2(&dst[b*512 + j], s0 + bb[j], s1 + bb[j+1]);
      }
    } else {
      const int bz = blk - 128;
      if (tid < 256) cst(&p.ctx2[bz*256 + tid], 0.f);
      if (bz == 127 && tid < 64) cst(&p.wsum[tid], 0.f);
      __syncthreads(); __syncthreads();
    }
    gbar(p.bar, ++bid);
  }
}

extern "C" void kernel_launch(void* const* d_in, const int* in_sizes, int n_in,
                              void* d_out, int out_size, void* d_ws, size_t ws_size,
                              hipStream_t stream){
  (void)in_sizes; (void)n_in; (void)out_size; (void)ws_size;
  char* w = (char*)d_ws;
  size_t off = 0;
  auto carve = [&](size_t bytes) -> char* {
    char* r = w + off; off += (bytes + 255) & ~(size_t)255; return r;
  };
  SlaP p;
  p.feat8  = (unsigned char*)carve((size_t)NB*TT*CC);
  p.scr8   = (unsigned char*)carve((size_t)NB*TT*HH);
  p.hid2   = (float*)carve((size_t)2*512*64*4);
  p.hproj  = (float*)carve((size_t)64*512*4);
  p.h1sg   = (float*)carve((size_t)64*512*4);
  p.h1lg   = (float*)carve((size_t)64*512*4);
  p.ctx2   = (float*)carve((size_t)512*64*4);
  p.wsum   = (float*)carve(64*4);
  p.chars  = (int*)carve(64*4);
  p.bar    = (unsigned*)carve(2048);

  p.score_w = (const float*)d_in[4];
  p.w_ih  = (const float*)d_in[5];  p.w_hh  = (const float*)d_in[6];
  p.b_ih  = (const float*)d_in[7];  p.b_hh  = (const float*)d_in[8];
  p.h2h_w = (const float*)d_in[2];  p.h2h_b = (const float*)d_in[3];
  p.sg1_w = (const float*)d_in[9];  p.sg1_b = (const float*)d_in[10];
  p.sg2_w = (const float*)d_in[11]; p.sg2_b = (const float*)d_in[12];
  p.lg1_w = (const float*)d_in[13]; p.lg1_b = (const float*)d_in[14];
  p.lg2_w = (const float*)d_in[15]; p.lg2_b = (const float*)d_in[16];
  p.out_probs = (float*)d_out;
  p.out_loc   = p.out_probs + (size_t)NB*STEPS*NCLS;

  const float* fea = (const float*)d_in[0];
  const float* i2h = (const float*)d_in[1];

  k_init<<<128, 256, 0, stream>>>(p);
  k_feat8<<<dim3(13, 8, 64), 256, 0, stream>>>(fea, p.feat8);
  k_fpgemm<<<dim3(13, 8, 64), 256, 0, stream>>>(fea, i2h, p.scr8);
  sla_main<<<GRID_MAIN, THR_MAIN, 0, stream>>>(p);
}